// Round 5
// baseline (408.843 us; speedup 1.0000x reference)
//
#include <hip/hip_runtime.h>
#include <hip/hip_cooperative_groups.h>

namespace cg = cooperative_groups;

// Problem constants
#define NROWS 512          // N
#define FEAT  8192         // NUM_CHANNELS*4*4
#define BDIM  64
#define CDIM  16
#define MCOLS 1024         // BDIM*CDIM
#define OUTC  8256         // FEAT + BDIM
#define KSPLIT 8
#define KCHUNK (FEAT / KSPLIT)     // 1024
#define MSIZE  (NROWS * MCOLS)     // 524288 floats = 2 MB

#define SMEM_BYTES 43008   // max(prep 33280, gemm 16384, pairwise 43008)

typedef __bf16 bf16x8 __attribute__((ext_vector_type(8)));
typedef float  floatx4 __attribute__((ext_vector_type(4)));

#define AS1 __attribute__((address_space(1)))
#define AS3 __attribute__((address_space(3)))

// async global->LDS, 16B per lane. LDS dest = wave-uniform base + lane*16.
static __device__ __forceinline__ void gload16(const void* g, void* l) {
    __builtin_amdgcn_global_load_lds((AS1 void*)(g), (AS3 void*)(l), 16, 0, 0);
}

static __device__ __forceinline__ unsigned short f2bf(float f) {
    unsigned int x = __builtin_bit_cast(unsigned int, f);
    unsigned int r = (x + 0x7FFFu + ((x >> 16) & 1u)) >> 16;   // RNE
    return (unsigned short)r;
}

// ---------------------------------------------------------------------------
// Phase bodies (256 blocks x 512 threads each). Shared by the fused
// cooperative kernel and the 4-dispatch fallback path.
// ---------------------------------------------------------------------------

// prep: x fp32 -> bf16 xb + copy x into out[:, :8192]; then T (8192x1024 f32)
// -> Tt (1024x8192 bf16) via 64x64 LDS tiles, 2 tiles at a time.
static __device__ __forceinline__ void prep_body(
        int bid, int t, char* smem,
        const float* __restrict__ x, const float* __restrict__ T,
        unsigned short* __restrict__ xb, unsigned short* __restrict__ Tt,
        float* __restrict__ out) {
    // --- x conversion: 1M float4 total, 4096 per block (8 units x 512) ---
#pragma unroll
    for (int u = 0; u < 8; ++u) {
        int gid = bid * 4096 + u * 512 + t;          // float4 index
        float4 v = *(const float4*)(x + (size_t)gid * 4);
        ushort4 uu;
        uu.x = f2bf(v.x); uu.y = f2bf(v.y); uu.z = f2bf(v.z); uu.w = f2bf(v.w);
        *(ushort4*)(xb + (size_t)gid * 4) = uu;
        int row = gid >> 11, col4 = gid & 2047;
        *(float4*)(out + (size_t)row * OUTC + col4 * 4) = v;
    }
    // --- T transpose: 2048 tiles of 64x64; 8 per block, 2 concurrently ---
    float (*lds)[64][65] = (float (*)[64][65])smem;  // 2 buffers, +1 pad
    int sub = t >> 8, tt = t & 255;
    for (int u = 0; u < 4; ++u) {
        int tile = bid * 8 + u * 2 + sub;
        int kt = tile & 127, nt = tile >> 7;         // 128 k-tiles x 16 n-tiles
        __syncthreads();                              // protect prior reads
        int kk = tt >> 2, q = tt & 3;
#pragma unroll
        for (int p = 0; p < 4; ++p) {
            int c4 = q + p * 4;
            float4 v = *(const float4*)(T + (size_t)(kt * 64 + kk) * MCOLS + nt * 64 + c4 * 4);
            lds[sub][kk][c4 * 4 + 0] = v.x; lds[sub][kk][c4 * 4 + 1] = v.y;
            lds[sub][kk][c4 * 4 + 2] = v.z; lds[sub][kk][c4 * 4 + 3] = v.w;
        }
        __syncthreads();
        int nr = tt >> 2, ck = tt & 3;
        unsigned int wv[8];
#pragma unroll
        for (int j = 0; j < 8; ++j) {
            unsigned int lo = f2bf(lds[sub][ck * 16 + j * 2 + 0][nr]);
            unsigned int hi = f2bf(lds[sub][ck * 16 + j * 2 + 1][nr]);
            wv[j] = lo | (hi << 16);
        }
        uint4* dst = (uint4*)(Tt + (size_t)(nt * 64 + nr) * FEAT + kt * 64 + ck * 16);
        dst[0] = make_uint4(wv[0], wv[1], wv[2], wv[3]);
        dst[1] = make_uint4(wv[4], wv[5], wv[6], wv[7]);
    }
}

// gemm: M = x@T, bf16 MFMA 16x16x32, 128x128 tile, 8 waves (2x4), BK=32,
// global_load_lds staging with XOR-swizzled source chunks. split-K=8.
// grid = 4(mt) x 8(nt) x 8(ks) = 256 blocks.
static __device__ __forceinline__ void gemm_body(
        int bid, int t, char* smem,
        const unsigned short* __restrict__ xb, const unsigned short* __restrict__ Tt,
        float* __restrict__ Mp) {
    unsigned short* ldsA = (unsigned short*)smem;         // 128 rows x 32 (64B/row)
    unsigned short* ldsB = (unsigned short*)(smem + 8192);
    int mt = bid & 3, nt = (bid >> 2) & 7, ks = bid >> 5;
    int m0 = mt * 128, n0 = nt * 128, kbase = ks * KCHUNK;
    int w = t >> 6, l = t & 63;

    // staging: wave w -> rows [w*16, w*16+16) of both A and B tiles.
    // lane l -> row r0 = w*16 + (l>>2), slot s = l&3, global chunk
    // c = s ^ ((r0>>1)&3); LDS dest forced to base + l*16.
    int r0 = w * 16 + (l >> 2);
    int c  = (l & 3) ^ ((r0 >> 1) & 3);
    const unsigned short* gA = xb + (size_t)(m0 + r0) * FEAT + kbase + c * 8;
    const unsigned short* gB = Tt + (size_t)(n0 + r0) * FEAT + kbase + c * 8;
    unsigned short* lA = ldsA + w * 512;
    unsigned short* lB = ldsB + w * 512;

    // compute: wave (wr = w>>2, wc = w&3) covers rows wr*64+[0,64), cols wc*32+[0,32)
    int wr = w >> 2, wc = w & 3, fm = l & 15, fq = l >> 4;
    int swz = (fm >> 1) & 3;
    const unsigned short* pa[4];
    const unsigned short* pb[2];
#pragma unroll
    for (int a = 0; a < 4; ++a)
        pa[a] = ldsA + (wr * 64 + a * 16 + fm) * 32 + ((fq ^ swz) * 8);
#pragma unroll
    for (int b = 0; b < 2; ++b)
        pb[b] = ldsB + (wc * 32 + b * 16 + fm) * 32 + ((fq ^ swz) * 8);

    floatx4 acc[4][2] = {};

    for (int kk = 0; kk < KCHUNK; kk += 32) {
        __syncthreads();                      // protect LDS from overwrite
        gload16(gA + kk, lA);
        gload16(gB + kk, lB);
        __syncthreads();                      // drains vmcnt -> LDS visible
        bf16x8 af[4], bfr[2];
#pragma unroll
        for (int a = 0; a < 4; ++a) af[a] = *(const bf16x8*)pa[a];
#pragma unroll
        for (int b = 0; b < 2; ++b) bfr[b] = *(const bf16x8*)pb[b];
#pragma unroll
        for (int a = 0; a < 4; ++a)
#pragma unroll
            for (int b = 0; b < 2; ++b)
                acc[a][b] = __builtin_amdgcn_mfma_f32_16x16x32_bf16(af[a], bfr[b], acc[a][b], 0, 0, 0);
    }

    // epilogue: D layout col = l&15, row = (l>>4)*4 + r
    float* outp = Mp + (size_t)ks * MSIZE;
    int gr0 = m0 + wr * 64, gc0 = n0 + wc * 32;
#pragma unroll
    for (int a = 0; a < 4; ++a)
#pragma unroll
        for (int r = 0; r < 4; ++r) {
            int row = gr0 + a * 16 + fq * 4 + r;
#pragma unroll
            for (int b = 0; b < 2; ++b)
                outp[(size_t)row * MCOLS + gc0 + b * 16 + fm] = acc[a][b][r];
        }
}

// reduce: Ms = sum of 8 split-K partials. 256 blocks x 512 thr, float4 each.
static __device__ __forceinline__ void reduce_body(
        int bid, int t, const float* __restrict__ Mp, float* __restrict__ Ms) {
    int gid = bid * 512 + t;                  // float4 index, 0..131071
    const float4* p = (const float4*)Mp;
    float4 s = p[gid];
#pragma unroll
    for (int k = 1; k < KSPLIT; ++k) {
        float4 v = p[(size_t)k * (MSIZE / 4) + gid];
        s.x += v.x; s.y += v.y; s.z += v.z; s.w += v.w;
    }
    ((float4*)Ms)[gid] = s;
}

// pairwise: o[i,b] = sum_j exp(-L1(M_i,M_j)) -> out[:, 8192:8256].
// 256 blocks: b = bid&63, it-pair = bid>>6. Thread groups g = t>>8 handle
// it = itp*2+g; within a group 4 waves split j. j wave-uniform -> broadcast.
static __device__ __forceinline__ void pairwise_body(
        int bid, int t, char* smem,
        const float* __restrict__ Ms, float* __restrict__ out) {
    float* ldsM = (float*)smem;               // 512 rows x 20 floats (pad)
    float (*partial)[64] = (float (*)[64])(smem + 40960);   // [8][64]
    int b = bid & 63, itp = bid >> 6;
#pragma unroll
    for (int p = 0; p < 4; ++p) {
        int idx = t + p * 512;                // 2048 float4 total
        int j = idx >> 2, c4 = idx & 3;
        float4 v = *(const float4*)(Ms + (size_t)j * MCOLS + b * CDIM + c4 * 4);
        *(float4*)&ldsM[j * 20 + c4 * 4] = v;
    }
    __syncthreads();

    int lane = t & 63, w = t >> 6, g = t >> 8, wg = (t >> 6) & 3;
    int i = (itp * 2 + g) * 64 + lane;
    float mi[CDIM];
#pragma unroll
    for (int cc = 0; cc < CDIM; ++cc) mi[cc] = ldsM[i * 20 + cc];

    float acc = 0.0f;
    for (int jj = wg * 128; jj < wg * 128 + 128; ++jj) {
        float d = 0.0f;
#pragma unroll
        for (int cc = 0; cc < CDIM; ++cc) d += fabsf(mi[cc] - ldsM[jj * 20 + cc]);
        acc += __expf(-d);
    }
    partial[w][lane] = acc;
    __syncthreads();
    if ((t & 255) < 64) {
        int ii = (itp * 2 + g) * 64 + (t & 63);
        float o = partial[g * 4 + 0][t & 63] + partial[g * 4 + 1][t & 63] +
                  partial[g * 4 + 2][t & 63] + partial[g * 4 + 3][t & 63];
        out[(size_t)ii * OUTC + FEAT + b] = o;
    }
}

// ---------------------------------------------------------------------------
// Fused cooperative kernel: 256 blocks x 512 threads.
// ---------------------------------------------------------------------------
__global__ __launch_bounds__(512, 2) void fused_kernel(
        const float* __restrict__ x, const float* __restrict__ T,
        unsigned short* __restrict__ xb, unsigned short* __restrict__ Tt,
        float* __restrict__ Mp, float* __restrict__ Ms,
        float* __restrict__ out) {
    __shared__ __align__(16) char smem[SMEM_BYTES];
    cg::grid_group grid = cg::this_grid();
    int bid = blockIdx.x, t = threadIdx.x;

    prep_body(bid, t, smem, x, T, xb, Tt, out);
    __threadfence();
    grid.sync();
    gemm_body(bid, t, smem, xb, Tt, Mp);
    __threadfence();
    grid.sync();
    reduce_body(bid, t, Mp, Ms);
    __threadfence();
    grid.sync();
    pairwise_body(bid, t, smem, Ms, out);
}

// ---------------------------------------------------------------------------
// Fallback path: same bodies as 4 separate dispatches.
// ---------------------------------------------------------------------------
__global__ __launch_bounds__(512, 2) void k_prep(const float* __restrict__ x,
                                                 const float* __restrict__ T,
                                                 unsigned short* __restrict__ xb,
                                                 unsigned short* __restrict__ Tt,
                                                 float* __restrict__ out) {
    __shared__ __align__(16) char smem[33280];
    prep_body(blockIdx.x, threadIdx.x, smem, x, T, xb, Tt, out);
}
__global__ __launch_bounds__(512, 2) void k_gemm(const unsigned short* __restrict__ xb,
                                                 const unsigned short* __restrict__ Tt,
                                                 float* __restrict__ Mp) {
    __shared__ __align__(16) char smem[16384];
    gemm_body(blockIdx.x, threadIdx.x, smem, xb, Tt, Mp);
}
__global__ __launch_bounds__(512, 2) void k_reduce(const float* __restrict__ Mp,
                                                   float* __restrict__ Ms) {
    reduce_body(blockIdx.x, threadIdx.x, Mp, Ms);
}
__global__ __launch_bounds__(512, 2) void k_pair(const float* __restrict__ Ms,
                                                 float* __restrict__ out) {
    __shared__ __align__(16) char smem[43008];
    pairwise_body(blockIdx.x, threadIdx.x, smem, Ms, out);
}

// ---------------------------------------------------------------------------
extern "C" void kernel_launch(void* const* d_in, const int* in_sizes, int n_in,
                              void* d_out, int out_size, void* d_ws, size_t ws_size,
                              hipStream_t stream) {
    const float* x = (const float*)d_in[0];      // (512, 8192)
    const float* T = (const float*)d_in[1];      // (8192, 1024)
    float* out = (float*)d_out;                  // (512, 8256)

    // ws layout: xb 8MB | Tt 16MB | Mp 8x2MB=16MB | Msum 2MB  (42MB total)
    unsigned short* xb = (unsigned short*)d_ws;
    unsigned short* Tt = (unsigned short*)((char*)d_ws + (8u << 20));
    float*          Mp = (float*)((char*)d_ws + (24u << 20));
    float*          Ms = (float*)((char*)d_ws + (40u << 20));

    // Host-only queries (graph-capture safe, deterministic every call):
    int dev = 0; hipGetDevice(&dev);
    int coop = 0; hipDeviceGetAttribute(&coop, hipDeviceAttributeCooperativeLaunch, dev);
    int ncu = 0;  hipDeviceGetAttribute(&ncu, hipDeviceAttributeMultiprocessorCount, dev);
    int nb = 0;
    hipOccupancyMaxActiveBlocksPerMultiprocessor(&nb, (const void*)fused_kernel, 512, 0);

    if (coop && nb > 0 && nb * ncu >= 256) {
        void* args[] = {(void*)&x, (void*)&T, (void*)&xb, (void*)&Tt,
                        (void*)&Mp, (void*)&Ms, (void*)&out};
        hipLaunchCooperativeKernel((const void*)fused_kernel, dim3(256), dim3(512),
                                   args, 0, stream);
    } else {
        k_prep<<<256, 512, 0, stream>>>(x, T, xb, Tt, out);
        k_gemm<<<256, 512, 0, stream>>>(xb, Tt, Mp);
        k_reduce<<<256, 512, 0, stream>>>(Mp, Ms);
        k_pair<<<256, 512, 0, stream>>>(Ms, out);
    }
}

// Round 6
// 138.843 us; speedup vs baseline: 2.9446x; 2.9446x over previous
//
#include <hip/hip_runtime.h>

// Problem constants
#define NROWS 512          // N
#define FEAT  8192         // NUM_CHANNELS*4*4
#define BDIM  64
#define CDIM  16
#define MCOLS 1024         // BDIM*CDIM
#define OUTC  8256         // FEAT + BDIM
#define KSPLIT 8
#define KCHUNK (FEAT / KSPLIT)     // 1024
#define MSIZE  (NROWS * MCOLS)     // 524288 floats = 2 MB

typedef __bf16 bf16x8 __attribute__((ext_vector_type(8)));
typedef float  floatx4 __attribute__((ext_vector_type(4)));

#define AS1 __attribute__((address_space(1)))
#define AS3 __attribute__((address_space(3)))

// async global->LDS, 16B per lane. LDS dest = wave-uniform base + lane*16.
static __device__ __forceinline__ void gload16(const void* g, void* l) {
    __builtin_amdgcn_global_load_lds((AS1 void*)(g), (AS3 void*)(l), 16, 0, 0);
}

static __device__ __forceinline__ unsigned short f2bf(float f) {
    unsigned int x = __builtin_bit_cast(unsigned int, f);
    unsigned int r = (x + 0x7FFFu + ((x >> 16) & 1u)) >> 16;   // RNE
    return (unsigned short)r;
}

// ---------------------------------------------------------------------------
// k_prep: 256 blocks x 512 thr.
//  (a) x fp32 -> bf16 xb + copy x into out[:, :8192]  (8 units x 512 float4)
//  (b) T (8192x1024 f32) -> Tt (1024x8192 bf16), 64x64 LDS tiles, 2 at a time
// ---------------------------------------------------------------------------
__global__ __launch_bounds__(512, 2) void k_prep(const float* __restrict__ x,
                                                 const float* __restrict__ T,
                                                 unsigned short* __restrict__ xb,
                                                 unsigned short* __restrict__ Tt,
                                                 float* __restrict__ out) {
    __shared__ __align__(16) float lds[2][64][65];   // +1 pad: 2-way only (free)
    int bid = blockIdx.x, t = threadIdx.x;
#pragma unroll
    for (int u = 0; u < 8; ++u) {
        int gid = bid * 4096 + u * 512 + t;          // float4 index, 1M total
        float4 v = *(const float4*)(x + (size_t)gid * 4);
        ushort4 uu;
        uu.x = f2bf(v.x); uu.y = f2bf(v.y); uu.z = f2bf(v.z); uu.w = f2bf(v.w);
        *(ushort4*)(xb + (size_t)gid * 4) = uu;
        int row = gid >> 11, col4 = gid & 2047;
        *(float4*)(out + (size_t)row * OUTC + col4 * 4) = v;
    }
    // T transpose: 2048 tiles of 64x64; 8 per block, 2 concurrently
    int sub = t >> 8, tt = t & 255;
    for (int u = 0; u < 4; ++u) {
        int tile = bid * 8 + u * 2 + sub;
        int kt = tile & 127, nt = tile >> 7;         // 128 k-tiles x 16 n-tiles
        __syncthreads();                              // protect prior reads
        int kk = tt >> 2, q = tt & 3;
#pragma unroll
        for (int p = 0; p < 4; ++p) {
            int c4 = q + p * 4;
            float4 v = *(const float4*)(T + (size_t)(kt * 64 + kk) * MCOLS + nt * 64 + c4 * 4);
            lds[sub][kk][c4 * 4 + 0] = v.x; lds[sub][kk][c4 * 4 + 1] = v.y;
            lds[sub][kk][c4 * 4 + 2] = v.z; lds[sub][kk][c4 * 4 + 3] = v.w;
        }
        __syncthreads();
        int nr = tt >> 2, ck = tt & 3;
        unsigned int wv[8];
#pragma unroll
        for (int j = 0; j < 8; ++j) {
            unsigned int lo = f2bf(lds[sub][ck * 16 + j * 2 + 0][nr]);
            unsigned int hi = f2bf(lds[sub][ck * 16 + j * 2 + 1][nr]);
            wv[j] = lo | (hi << 16);
        }
        uint4* dst = (uint4*)(Tt + (size_t)(nt * 64 + nr) * FEAT + kt * 64 + ck * 16);
        dst[0] = make_uint4(wv[0], wv[1], wv[2], wv[3]);
        dst[1] = make_uint4(wv[4], wv[5], wv[6], wv[7]);
    }
}

// ---------------------------------------------------------------------------
// k_gemm: M = x@T, bf16 MFMA 16x16x32, 128x128 tile, 8 waves (2x4), BK=32,
// global_load_lds staging with XOR-swizzled source chunks. split-K=8.
// grid = 4(mt) x 8(nt) x 8(ks) = 256 blocks x 512 thr.
// ---------------------------------------------------------------------------
__global__ __launch_bounds__(512, 2) void k_gemm(const unsigned short* __restrict__ xb,
                                                 const unsigned short* __restrict__ Tt,
                                                 float* __restrict__ Mp) {
    __shared__ __align__(16) unsigned short ldsA[128 * 32];   // 8 KB, 64B/row
    __shared__ __align__(16) unsigned short ldsB[128 * 32];
    int bid = blockIdx.x, t = threadIdx.x;
    int mt = bid & 3, nt = (bid >> 2) & 7, ks = bid >> 5;
    int m0 = mt * 128, n0 = nt * 128, kbase = ks * KCHUNK;
    int w = t >> 6, l = t & 63;

    // staging: wave w -> rows [w*16, w*16+16) of both A and B tiles.
    // lane l -> row r0 = w*16 + (l>>2), slot s = l&3, global chunk
    // c = s ^ ((r0>>1)&3); LDS dest forced to base + l*16.
    int r0 = w * 16 + (l >> 2);
    int c  = (l & 3) ^ ((r0 >> 1) & 3);
    const unsigned short* gA = xb + (size_t)(m0 + r0) * FEAT + kbase + c * 8;
    const unsigned short* gB = Tt + (size_t)(n0 + r0) * FEAT + kbase + c * 8;
    unsigned short* lA = ldsA + w * 512;
    unsigned short* lB = ldsB + w * 512;

    // compute: wave (wr = w>>2, wc = w&3) covers rows wr*64+[0,64), cols wc*32+[0,32)
    int wr = w >> 2, wc = w & 3, fm = l & 15, fq = l >> 4;
    int swz = (fm >> 1) & 3;
    const unsigned short* pa[4];
    const unsigned short* pb[2];
#pragma unroll
    for (int a = 0; a < 4; ++a)
        pa[a] = ldsA + (wr * 64 + a * 16 + fm) * 32 + ((fq ^ swz) * 8);
#pragma unroll
    for (int b = 0; b < 2; ++b)
        pb[b] = ldsB + (wc * 32 + b * 16 + fm) * 32 + ((fq ^ swz) * 8);

    floatx4 acc[4][2] = {};

    for (int kk = 0; kk < KCHUNK; kk += 32) {
        __syncthreads();                      // protect LDS from overwrite
        gload16(gA + kk, lA);
        gload16(gB + kk, lB);
        __syncthreads();                      // drains vmcnt -> LDS visible
        bf16x8 af[4], bfr[2];
#pragma unroll
        for (int a = 0; a < 4; ++a) af[a] = *(const bf16x8*)pa[a];
#pragma unroll
        for (int b = 0; b < 2; ++b) bfr[b] = *(const bf16x8*)pb[b];
#pragma unroll
        for (int a = 0; a < 4; ++a)
#pragma unroll
            for (int b = 0; b < 2; ++b)
                acc[a][b] = __builtin_amdgcn_mfma_f32_16x16x32_bf16(af[a], bfr[b], acc[a][b], 0, 0, 0);
    }

    // epilogue: D layout col = l&15, row = (l>>4)*4 + r
    float* outp = Mp + (size_t)ks * MSIZE;
    int gr0 = m0 + wr * 64, gc0 = n0 + wc * 32;
#pragma unroll
    for (int a = 0; a < 4; ++a)
#pragma unroll
        for (int r = 0; r < 4; ++r) {
            int row = gr0 + a * 16 + fq * 4 + r;
#pragma unroll
            for (int b = 0; b < 2; ++b)
                outp[(size_t)row * MCOLS + gc0 + b * 16 + fm] = acc[a][b][r];
        }
}

// ---------------------------------------------------------------------------
// k_pair: o[i,b] = sum_j exp(-L1(M_i,M_j)) -> out[:, 8192:8256].
// Split-K reduction fused into LDS staging (reads 8 Mp partials, LLC-hot).
// 256 blocks: b = bid&63, itp = bid>>6. Groups g = t>>8 handle it = itp*2+g;
// within a group 4 waves split j. j wave-uniform -> LDS broadcast reads.
// ---------------------------------------------------------------------------
__global__ __launch_bounds__(512, 2) void k_pair(const float* __restrict__ Mp,
                                                 float* __restrict__ out) {
    __shared__ float ldsM[NROWS * 20];                  // 40960 B, padded rows
    __shared__ float partial[8][64];
    int bid = blockIdx.x, t = threadIdx.x;
    int b = bid & 63, itp = bid >> 6;
#pragma unroll
    for (int p = 0; p < 4; ++p) {
        int idx = t + p * 512;                // 2048 float4 total
        int j = idx >> 2, c4 = idx & 3;
        const float* base = Mp + (size_t)j * MCOLS + b * CDIM + c4 * 4;
        float4 s = *(const float4*)base;
#pragma unroll
        for (int k = 1; k < KSPLIT; ++k) {
            float4 v = *(const float4*)(base + (size_t)k * MSIZE);
            s.x += v.x; s.y += v.y; s.z += v.z; s.w += v.w;
        }
        *(float4*)&ldsM[j * 20 + c4 * 4] = s;
    }
    __syncthreads();

    int lane = t & 63, w = t >> 6, g = t >> 8, wg = (t >> 6) & 3;
    int i = (itp * 2 + g) * 64 + lane;
    float mi[CDIM];
#pragma unroll
    for (int cc = 0; cc < CDIM; ++cc) mi[cc] = ldsM[i * 20 + cc];

    float acc = 0.0f;
    for (int jj = wg * 128; jj < wg * 128 + 128; ++jj) {
        float d = 0.0f;
#pragma unroll
        for (int cc = 0; cc < CDIM; ++cc) d += fabsf(mi[cc] - ldsM[jj * 20 + cc]);
        acc += __expf(-d);
    }
    partial[w][lane] = acc;
    __syncthreads();
    if ((t & 255) < 64) {
        int ii = (itp * 2 + g) * 64 + (t & 63);
        float o = partial[g * 4 + 0][t & 63] + partial[g * 4 + 1][t & 63] +
                  partial[g * 4 + 2][t & 63] + partial[g * 4 + 3][t & 63];
        out[(size_t)ii * OUTC + FEAT + b] = o;
    }
}

// ---------------------------------------------------------------------------
extern "C" void kernel_launch(void* const* d_in, const int* in_sizes, int n_in,
                              void* d_out, int out_size, void* d_ws, size_t ws_size,
                              hipStream_t stream) {
    const float* x = (const float*)d_in[0];      // (512, 8192)
    const float* T = (const float*)d_in[1];      // (8192, 1024)
    float* out = (float*)d_out;                  // (512, 8256)

    // ws layout: xb 8MB | Tt 16MB | Mp 8x2MB=16MB  (40MB total)
    unsigned short* xb = (unsigned short*)d_ws;
    unsigned short* Tt = (unsigned short*)((char*)d_ws + (8u << 20));
    float*          Mp = (float*)((char*)d_ws + (24u << 20));

    k_prep<<<256, 512, 0, stream>>>(x, T, xb, Tt, out);
    k_gemm<<<256, 512, 0, stream>>>(xb, Tt, Mp);
    k_pair<<<256, 512, 0, stream>>>(Mp, out);
}

// Round 7
// 135.952 us; speedup vs baseline: 3.0073x; 1.0213x over previous
//
#include <hip/hip_runtime.h>

// Problem constants
#define NROWS 512          // N
#define FEAT  8192         // NUM_CHANNELS*4*4
#define BDIM  64
#define CDIM  16
#define MCOLS 1024         // BDIM*CDIM
#define OUTC  8256         // FEAT + BDIM
#define KSPLIT 8
#define KCHUNK (FEAT / KSPLIT)     // 1024
#define MSIZE  (NROWS * MCOLS)     // 524288 floats = 2 MB

typedef __bf16 bf16x8 __attribute__((ext_vector_type(8)));
typedef float  floatx4 __attribute__((ext_vector_type(4)));

#define AS1 __attribute__((address_space(1)))
#define AS3 __attribute__((address_space(3)))

// async global->LDS, 16B per lane. LDS dest = wave-uniform base + lane*16.
static __device__ __forceinline__ void gload16(const void* g, void* l) {
    __builtin_amdgcn_global_load_lds((AS1 void*)(g), (AS3 void*)(l), 16, 0, 0);
}

static __device__ __forceinline__ unsigned short f2bf(float f) {
    unsigned int x = __builtin_bit_cast(unsigned int, f);
    unsigned int r = (x + 0x7FFFu + ((x >> 16) & 1u)) >> 16;   // RNE
    return (unsigned short)r;
}

// ---------------------------------------------------------------------------
// k_prep: 256 blocks x 512 thr.  (verbatim from R6 — passed, HBM-bound)
//  (a) x fp32 -> bf16 xb + copy x into out[:, :8192]  (8 units x 512 float4)
//  (b) T (8192x1024 f32) -> Tt (1024x8192 bf16), 64x64 LDS tiles, 2 at a time
// ---------------------------------------------------------------------------
__global__ __launch_bounds__(512, 2) void k_prep(const float* __restrict__ x,
                                                 const float* __restrict__ T,
                                                 unsigned short* __restrict__ xb,
                                                 unsigned short* __restrict__ Tt,
                                                 float* __restrict__ out) {
    __shared__ __align__(16) float lds[2][64][65];   // +1 pad: 2-way only (free)
    int bid = blockIdx.x, t = threadIdx.x;
#pragma unroll
    for (int u = 0; u < 8; ++u) {
        int gid = bid * 4096 + u * 512 + t;          // float4 index, 1M total
        float4 v = *(const float4*)(x + (size_t)gid * 4);
        ushort4 uu;
        uu.x = f2bf(v.x); uu.y = f2bf(v.y); uu.z = f2bf(v.z); uu.w = f2bf(v.w);
        *(ushort4*)(xb + (size_t)gid * 4) = uu;
        int row = gid >> 11, col4 = gid & 2047;
        *(float4*)(out + (size_t)row * OUTC + col4 * 4) = v;
    }
    // T transpose: 2048 tiles of 64x64; 8 per block, 2 concurrently
    int sub = t >> 8, tt = t & 255;
    for (int u = 0; u < 4; ++u) {
        int tile = bid * 8 + u * 2 + sub;
        int kt = tile & 127, nt = tile >> 7;         // 128 k-tiles x 16 n-tiles
        __syncthreads();                              // protect prior reads
        int kk = tt >> 2, q = tt & 3;
#pragma unroll
        for (int p = 0; p < 4; ++p) {
            int c4 = q + p * 4;
            float4 v = *(const float4*)(T + (size_t)(kt * 64 + kk) * MCOLS + nt * 64 + c4 * 4);
            lds[sub][kk][c4 * 4 + 0] = v.x; lds[sub][kk][c4 * 4 + 1] = v.y;
            lds[sub][kk][c4 * 4 + 2] = v.z; lds[sub][kk][c4 * 4 + 3] = v.w;
        }
        __syncthreads();
        int nr = tt >> 2, ck = tt & 3;
        unsigned int wv[8];
#pragma unroll
        for (int j = 0; j < 8; ++j) {
            unsigned int lo = f2bf(lds[sub][ck * 16 + j * 2 + 0][nr]);
            unsigned int hi = f2bf(lds[sub][ck * 16 + j * 2 + 1][nr]);
            wv[j] = lo | (hi << 16);
        }
        uint4* dst = (uint4*)(Tt + (size_t)(nt * 64 + nr) * FEAT + kt * 64 + ck * 16);
        dst[0] = make_uint4(wv[0], wv[1], wv[2], wv[3]);
        dst[1] = make_uint4(wv[4], wv[5], wv[6], wv[7]);
    }
}

// ---------------------------------------------------------------------------
// k_gemm: M = x@T, bf16 MFMA 16x16x32. 128x64 tile, 256 thr (4 waves, 2x2),
// BK=64 (16 K-iters), global_load_lds with XOR-swizzled chunks. split-K=8.
// grid = 4(mt) x 16(nt) x 8(ks) = 512 blocks -> exactly 2 blocks/CU so a
// second block computes while the first drains vmcnt at its barrier.
// LDS panels: 1 KB = [16 rows x 64 B(=32 k-half)] ; panel (rr,h) at
// (rr*2+h)*512 ushorts. Slot s within a row-half holds global chunk
// s ^ ((row>>1)&3); frag read slot = fq ^ ((fm>>1)&3)  -> chunk fq.
// ---------------------------------------------------------------------------
__global__ __launch_bounds__(256, 2) void k_gemm(const unsigned short* __restrict__ xb,
                                                 const unsigned short* __restrict__ Tt,
                                                 float* __restrict__ Mp) {
    __shared__ __align__(16) unsigned short ldsA[128 * 64];   // 16 KB, 16 panels
    __shared__ __align__(16) unsigned short ldsB[64 * 64];    // 8 KB, 8 panels
    int bid = blockIdx.x, t = threadIdx.x;
    int mt = bid & 3, nt = (bid >> 2) & 15, ks = bid >> 6;
    int m0 = mt * 128, n0 = nt * 64, kbase = ks * KCHUNK;
    int w = t >> 6, l = t & 63;

    // staging: lane l -> row range_base + (l>>2), slot s = l&3, global chunk
    // c = s ^ (((l>>2)>>1)&3) = s ^ ((l>>3)&3)  (range bases are mult. of 16).
    int c  = (l & 3) ^ ((l >> 3) & 3);
    int lr = l >> 2;
    // A rows: wave w covers [w*32, w*32+32) = ranges rr = 2w, 2w+1
    const unsigned short* gA0 = xb + (size_t)(m0 + w * 32 + lr) * FEAT + kbase + c * 8;
    const unsigned short* gA1 = gA0 + (size_t)16 * FEAT;
    // B rows: wave w covers [w*16, w*16+16) = range rr = w
    const unsigned short* gB0 = Tt + (size_t)(n0 + w * 16 + lr) * FEAT + kbase + c * 8;
    unsigned short* lA00 = ldsA + (4 * w + 0) * 512;   // (rr=2w,   h=0)
    unsigned short* lA01 = ldsA + (4 * w + 1) * 512;   // (rr=2w,   h=1)
    unsigned short* lA10 = ldsA + (4 * w + 2) * 512;   // (rr=2w+1, h=0)
    unsigned short* lA11 = ldsA + (4 * w + 3) * 512;   // (rr=2w+1, h=1)
    unsigned short* lB0  = ldsB + (2 * w + 0) * 512;   // (rr=w, h=0)
    unsigned short* lB1  = ldsB + (2 * w + 1) * 512;   // (rr=w, h=1)

    // compute: wave (wr = w>>1, wc = w&1): rows wr*64+[0,64), cols wc*32+[0,32)
    int wr = w >> 1, wc = w & 1, fm = l & 15, fq = l >> 4;
    int fo = fm * 32 + ((fq ^ ((fm >> 1) & 3)) * 8);
    const unsigned short* paB = ldsA + (wr * 8) * 512 + fo;  // + (a*2+h)*512
    const unsigned short* pbB = ldsB + (wc * 4) * 512 + fo;  // + (b*2+h)*512

    floatx4 acc[4][2] = {};

    for (int kk = 0; kk < KCHUNK; kk += 64) {
        __syncthreads();                      // protect LDS from overwrite
        gload16(gA0 + kk,      lA00);
        gload16(gA0 + kk + 32, lA01);
        gload16(gA1 + kk,      lA10);
        gload16(gA1 + kk + 32, lA11);
        gload16(gB0 + kk,      lB0);
        gload16(gB0 + kk + 32, lB1);
        __syncthreads();                      // drains vmcnt -> LDS visible
#pragma unroll
        for (int h = 0; h < 2; ++h) {
            bf16x8 af[4], bfr[2];
#pragma unroll
            for (int a = 0; a < 4; ++a) af[a]  = *(const bf16x8*)(paB + (a * 2 + h) * 512);
#pragma unroll
            for (int b = 0; b < 2; ++b) bfr[b] = *(const bf16x8*)(pbB + (b * 2 + h) * 512);
#pragma unroll
            for (int a = 0; a < 4; ++a)
#pragma unroll
                for (int b = 0; b < 2; ++b)
                    acc[a][b] = __builtin_amdgcn_mfma_f32_16x16x32_bf16(af[a], bfr[b], acc[a][b], 0, 0, 0);
        }
    }

    // epilogue: D layout col = l&15, row = (l>>4)*4 + r
    float* outp = Mp + (size_t)ks * MSIZE;
    int gr0 = m0 + wr * 64, gc0 = n0 + wc * 32;
#pragma unroll
    for (int a = 0; a < 4; ++a)
#pragma unroll
        for (int r = 0; r < 4; ++r) {
            int row = gr0 + a * 16 + fq * 4 + r;
#pragma unroll
            for (int b = 0; b < 2; ++b)
                outp[(size_t)row * MCOLS + gc0 + b * 16 + fm] = acc[a][b][r];
        }
}

// ---------------------------------------------------------------------------
// k_pair: o[i,b] = sum_j exp(-L1(M_i,M_j)) -> out[:, 8192:8256].
// (verbatim from R6 — passed) Split-K reduction fused into LDS staging.
// 256 blocks: b = bid&63, itp = bid>>6. Groups g = t>>8 handle it = itp*2+g;
// within a group 4 waves split j. j wave-uniform -> LDS broadcast reads.
// ---------------------------------------------------------------------------
__global__ __launch_bounds__(512, 2) void k_pair(const float* __restrict__ Mp,
                                                 float* __restrict__ out) {
    __shared__ float ldsM[NROWS * 20];                  // 40960 B, padded rows
    __shared__ float partial[8][64];
    int bid = blockIdx.x, t = threadIdx.x;
    int b = bid & 63, itp = bid >> 6;
#pragma unroll
    for (int p = 0; p < 4; ++p) {
        int idx = t + p * 512;                // 2048 float4 total
        int j = idx >> 2, c4 = idx & 3;
        const float* base = Mp + (size_t)j * MCOLS + b * CDIM + c4 * 4;
        float4 s = *(const float4*)base;
#pragma unroll
        for (int k = 1; k < KSPLIT; ++k) {
            float4 v = *(const float4*)(base + (size_t)k * MSIZE);
            s.x += v.x; s.y += v.y; s.z += v.z; s.w += v.w;
        }
        *(float4*)&ldsM[j * 20 + c4 * 4] = s;
    }
    __syncthreads();

    int lane = t & 63, w = t >> 6, g = t >> 8, wg = (t >> 6) & 3;
    int i = (itp * 2 + g) * 64 + lane;
    float mi[CDIM];
#pragma unroll
    for (int cc = 0; cc < CDIM; ++cc) mi[cc] = ldsM[i * 20 + cc];

    float acc = 0.0f;
    for (int jj = wg * 128; jj < wg * 128 + 128; ++jj) {
        float d = 0.0f;
#pragma unroll
        for (int cc = 0; cc < CDIM; ++cc) d += fabsf(mi[cc] - ldsM[jj * 20 + cc]);
        acc += __expf(-d);
    }
    partial[w][lane] = acc;
    __syncthreads();
    if ((t & 255) < 64) {
        int ii = (itp * 2 + g) * 64 + (t & 63);
        float o = partial[g * 4 + 0][t & 63] + partial[g * 4 + 1][t & 63] +
                  partial[g * 4 + 2][t & 63] + partial[g * 4 + 3][t & 63];
        out[(size_t)ii * OUTC + FEAT + b] = o;
    }
}

// ---------------------------------------------------------------------------
extern "C" void kernel_launch(void* const* d_in, const int* in_sizes, int n_in,
                              void* d_out, int out_size, void* d_ws, size_t ws_size,
                              hipStream_t stream) {
    const float* x = (const float*)d_in[0];      // (512, 8192)
    const float* T = (const float*)d_in[1];      // (8192, 1024)
    float* out = (float*)d_out;                  // (512, 8256)

    // ws layout: xb 8MB | Tt 16MB | Mp 8x2MB=16MB  (40MB total)
    unsigned short* xb = (unsigned short*)d_ws;
    unsigned short* Tt = (unsigned short*)((char*)d_ws + (8u << 20));
    float*          Mp = (float*)((char*)d_ws + (24u << 20));

    k_prep<<<256, 512, 0, stream>>>(x, T, xb, Tt, out);
    k_gemm<<<512, 256, 0, stream>>>(xb, Tt, Mp);
    k_pair<<<256, 512, 0, stream>>>(Mp, out);
}